// Round 9
// baseline (141.557 us; speedup 1.0000x reference)
//
#include <hip/hip_runtime.h>

typedef __attribute__((ext_vector_type(8))) short bf16x8;
typedef __attribute__((ext_vector_type(4))) float f32x4;

#define AS3 __attribute__((address_space(3)))
#define AS1 __attribute__((address_space(1)))

__device__ __forceinline__ unsigned short f2bf(float f) {
  unsigned u = __float_as_uint(f);
  u += 0x7fffu + ((u >> 16) & 1u);
  return (unsigned short)(u >> 16);
}
__device__ __forceinline__ float bf2f(unsigned short v) {
  return __uint_as_float((unsigned)v << 16);
}

// ---------------- kernel 1: transpose + pad + bf16 + border-zero + pool partials
__global__ void transpose_kernel(const float* __restrict__ x,
                                 unsigned short* __restrict__ xTp,
                                 float* __restrict__ part) {
  __shared__ unsigned short tb[64][258];
  __shared__ float redf[4][256];
  const int blk = blockIdx.x;
  const int b = blk >> 6, y = blk & 63;
  const int t = threadIdx.x;
  const int l = t & 63, w = t >> 6;
  const int coff = l >> 4;
  const int x4 = (l & 15) << 2;
  const float* src = x + (size_t)b * 256 * 4096 + (size_t)y * 64;
#pragma unroll 4
  for (int i = 0; i < 16; ++i) {
    const int c = w * 64 + i * 4 + coff;
    const float4 v = *reinterpret_cast<const float4*>(&src[(size_t)c * 4096 + x4]);
    tb[x4 + 0][c] = f2bf(v.x);
    tb[x4 + 1][c] = f2bf(v.y);
    tb[x4 + 2][c] = f2bf(v.z);
    tb[x4 + 3][c] = f2bf(v.w);
  }
  __syncthreads();
  unsigned short* dstb = xTp + (size_t)b * (4356 * 256);
  unsigned short* dst = dstb + ((size_t)(y + 1) * 66 + 1) * 256;
  float s0 = 0.f, s1 = 0.f, s2 = 0.f, s3 = 0.f;
#pragma unroll 4
  for (int i = 0; i < 16; ++i) {
    const int xx = w * 16 + i;
    ushort2 v0 = *(const ushort2*)&tb[xx][l * 4];
    ushort2 v1 = *(const ushort2*)&tb[xx][l * 4 + 2];
    s0 += bf2f(v0.x); s1 += bf2f(v0.y); s2 += bf2f(v1.x); s3 += bf2f(v1.y);
    ushort4 v = {v0.x, v0.y, v1.x, v1.y};
    *(ushort4*)&dst[(size_t)xx * 256 + l * 4] = v;
  }
  redf[w][l * 4 + 0] = s0;
  redf[w][l * 4 + 1] = s1;
  redf[w][l * 4 + 2] = s2;
  redf[w][l * 4 + 3] = s3;
  unsigned short* rowpad = dstb + ((size_t)(y + 1) * 66) * 256;
  rowpad[t] = 0;
  rowpad[65 * 256 + t] = 0;
  if (y == 0)
    for (int xx = 0; xx < 66; ++xx) dstb[(size_t)xx * 256 + t] = 0;
  if (y == 63)
    for (int xx = 0; xx < 66; ++xx) dstb[(size_t)(65 * 66 + xx) * 256 + t] = 0;
  __syncthreads();
  part[((size_t)(b * 64 + y)) * 256 + t] =
      redf[0][t] + redf[1][t] + redf[2][t] + redf[3][t];
}

// ---------------- kernel 1c: finish pool ----------
__global__ void poolfin_kernel(const float* __restrict__ part,
                               float* __restrict__ pooled) {
  const int b = blockIdx.x, c = threadIdx.x;
  float s = 0.f;
  for (int y = 0; y < 64; ++y) s += part[((size_t)(b * 64 + y)) * 256 + c];
  pooled[b * 256 + c] = s * (1.0f / 4096.0f);
}

// ---------------- kernel 2: attention MLP + softmax ----------------
__global__ void attn_kernel(const float* __restrict__ pooled,
                            const float* __restrict__ w1,
                            const float* __restrict__ bng,
                            const float* __restrict__ bnb,
                            const float* __restrict__ bnm,
                            const float* __restrict__ bnv,
                            const float* __restrict__ w2,
                            float* __restrict__ att) {
  __shared__ float hbuf[256];
  const int t = threadIdx.x;
  const int b = t >> 4, i = t & 15;
  float s = 0.f;
  for (int c = 0; c < 256; ++c) s += pooled[b * 256 + c] * w1[i * 256 + c];
  float h = (s - bnm[i]) * rsqrtf(bnv[i] + 1e-5f) * bng[i] + bnb[i];
  hbuf[t] = fmaxf(h, 0.f);
  __syncthreads();
  if (t < 64) {
    const int bb = t >> 2, k = t & 3;
    float l = 0.f;
    for (int j = 0; j < 16; ++j) l += hbuf[bb * 16 + j] * w2[k * 16 + j];
    float m = l;
    m = fmaxf(m, __shfl_xor(m, 1, 64));
    m = fmaxf(m, __shfl_xor(m, 2, 64));
    float e = expf(l - m);
    float sum = e;
    sum += __shfl_xor(sum, 1, 64);
    sum += __shfl_xor(sum, 2, 64);
    att[bb * 4 + k] = e / sum;
  }
}

// ---------------- kernel 3: aggregate per-sample kernels ----------------
__global__ void agg_kernel(const float* __restrict__ att,
                           const float* __restrict__ wgt,
                           unsigned short* __restrict__ agg) {
  const int o = blockIdx.x;
  const int bh = blockIdx.y;
  const int c = threadIdx.x;
  float w[4][9];
#pragma unroll
  for (int k = 0; k < 4; ++k) {
    const float* wp = wgt + ((size_t)((k << 8) + o) * 256 + c) * 9;
#pragma unroll
    for (int t = 0; t < 9; ++t) w[k][t] = wp[t];
  }
  __shared__ float attS[64];
  if (c < 64) attS[c] = att[c];
  __syncthreads();
#pragma unroll 1
  for (int b = bh * 8; b < bh * 8 + 8; ++b) {
    const float a0 = attS[b * 4 + 0], a1 = attS[b * 4 + 1];
    const float a2 = attS[b * 4 + 2], a3 = attS[b * 4 + 3];
#pragma unroll
    for (int t = 0; t < 9; ++t) {
      const float v = a0 * w[0][t] + a1 * w[1][t] + a2 * w[2][t] + a3 * w[3][t];
      agg[(((size_t)(b * 9 + t) * 256) + o) * 256 + c] = f2bf(v);
    }
  }
}

// ---------------- kernel 4: per-sample implicit-GEMM conv (bf16 MFMA) ----
// tile 256(p) x 128(cout); 4 waves (2Mx2N) of 128x64.
// A: LDS, double-buffered (2x28KB), staged once per c0, reused 9 taps.
// B: global->VGPR direct (L2-resident agg), depth-2 ping-pong.
// ONE barrier + one explicit vmcnt per 9 taps.
// R8 bugfix: B reload for tap t+2 is issued AFTER the MFMA cluster that
// consumes the set (was issued before -> clobbered operand, absmax 4.75).
__global__ __launch_bounds__(256, 2) void conv_kernel(
    const unsigned short* __restrict__ xTp,
    const unsigned short* __restrict__ agg,
    float* __restrict__ out) {
  __shared__ unsigned short lds[2 * 448 * 32];  // A dbuf: 57344 B

  const int bid = blockIdx.x;
  const int b = bid & 15;   // XCD = b%8
  const int rest = bid >> 4;
  const int mt = rest >> 1;
  const int nh = rest & 1;
  const int p0 = mt << 8;
  const int rowA0 = mt * 264;

  const int tid = threadIdx.x;
  const int lane = tid & 63;
  const int wave = tid >> 6;
  const int wm = wave >> 1;
  const int wn = wave & 1;

  const int srow = tid >> 2;
  const int scol = ((tid & 3) ^ ((tid >> 3) & 3)) << 3;
  const int sdst = srow * 64 + (tid & 3) * 16;

  const unsigned short* xbs =
      xTp + (size_t)b * (4356 * 256) + (size_t)rowA0 * 256 + scol;
  AS3 char* ldsA3 = (AS3 char*)lds;

  auto stageA = [&](int c0s, int bufb) {
#pragma unroll
    for (int i = 0; i < 7; ++i) {
      const int h = srow + (i << 6);
      const int hs = h > 395 ? 395 : h;
      __builtin_amdgcn_global_load_lds(
          (const AS1 void*)(xbs + (size_t)hs * 256 + c0s * 32),
          (AS3 void*)(ldsA3 + bufb + sdst + (i << 12)), 16, 0, 0);
    }
  };

  const int l15 = lane & 15;
  const int lhi = lane >> 4;
  const int hb0 = wm * 132 + l15;

  // B per-lane base: cout row = nh*128 + wn*64 + l15 (+n*16), k off = lhi*8
  const unsigned short* aggb = agg + (size_t)b * 9 * 256 * 256 +
                               (size_t)(nh * 128 + wn * 64 + l15) * 256 + lhi * 8;
  // B(tap, c0, n) = aggb + tap*65536 + n*4096 + c0*32

  f32x4 acc[8][4];
#pragma unroll
  for (int m = 0; m < 8; ++m)
#pragma unroll
    for (int n = 0; n < 4; ++n) acc[m][n] = (f32x4){0.f, 0.f, 0.f, 0.f};

#define LDA8(AQ, tap, bufb)                                                \
  {                                                                        \
    const int dy_ = (tap) / 3, dx_ = (tap) % 3;                            \
    _Pragma("unroll") for (int m = 0; m < 8; ++m) {                        \
      const int h_ = hb0 + ((m >> 2) + dy_) * 66 + (m & 3) * 16 + dx_;     \
      AQ[m] = *(const bf16x8*)((const char*)lds + (bufb) + h_ * 64 +       \
                               ((lhi ^ ((h_ >> 1) & 3)) << 4));            \
    }                                                                      \
  }

#define LDB4(BQ, tap)                                                      \
  _Pragma("unroll") for (int n = 0; n < 4; ++n) BQ[n] =                    \
      *(const bf16x8*)(aggb + (tap)*65536 + n * 4096 + c0 * 32);

#define MFMA32(AQ, BQ)                                                     \
  __builtin_amdgcn_s_setprio(1);                                           \
  _Pragma("unroll") for (int m = 0; m < 8; ++m)                            \
  _Pragma("unroll") for (int n = 0; n < 4; ++n)                            \
      acc[m][n] = __builtin_amdgcn_mfma_f32_16x16x32_bf16(AQ[m], BQ[n],    \
                                                          acc[m][n], 0, 0, 0); \
  __builtin_amdgcn_s_setprio(0);

// prefetch A(t+1); compute tap t; THEN reload the just-consumed B set
// with B(t+2) (WAR on BQc keeps ordering correct).
#define TAP(t, AQc, BQc, AQn, PA, PB)        \
  {                                          \
    if (PA) LDA8(AQn, (t) + 1, bufb);        \
    MFMA32(AQc, BQc);                        \
    if (PB) LDB4(BQc, (t) + 2);              \
    __builtin_amdgcn_sched_barrier(0);       \
  }

  stageA(0, 0);

#pragma unroll 1
  for (int c0 = 0; c0 < 8; ++c0) {
    const int bufb = (c0 & 1) * 28672;
    bf16x8 aq0[8], aq1[8], bq0[4], bq1[4];
    asm volatile("s_waitcnt vmcnt(0)" ::: "memory");  // A(c0) landed (per-wave)
    __builtin_amdgcn_s_barrier();                     // all waves' A landed
    __builtin_amdgcn_sched_barrier(0);
    if (c0 < 7) stageA(c0 + 1, bufb ^ 28672);
    LDB4(bq0, 0);
    LDB4(bq1, 1);
    LDA8(aq0, 0, bufb);
    TAP(0, aq0, bq0, aq1, 1, 1);
    TAP(1, aq1, bq1, aq0, 1, 1);
    TAP(2, aq0, bq0, aq1, 1, 1);
    TAP(3, aq1, bq1, aq0, 1, 1);
    TAP(4, aq0, bq0, aq1, 1, 1);
    TAP(5, aq1, bq1, aq0, 1, 1);
    TAP(6, aq0, bq0, aq1, 1, 1);
    TAP(7, aq1, bq1, aq0, 1, 0);
    TAP(8, aq0, bq0, aq1, 0, 0);
  }

  // epilogue: D row=(lane>>4)*4+reg is p, col=lane&15 is cout
#pragma unroll
  for (int m = 0; m < 8; ++m) {
    const int p = p0 + wm * 128 + (m >> 2) * 64 + (m & 3) * 16 + (lhi << 2);
#pragma unroll
    for (int n = 0; n < 4; ++n) {
      const int co = nh * 128 + wn * 64 + n * 16 + l15;
      float* dst = out + ((size_t)(b * 256 + co) << 12) + p;
      *reinterpret_cast<f32x4*>(dst) = acc[m][n];
    }
  }
#undef LDA8
#undef LDB4
#undef MFMA32
#undef TAP
}

extern "C" void kernel_launch(void* const* d_in, const int* in_sizes, int n_in,
                              void* d_out, int out_size, void* d_ws, size_t ws_size,
                              hipStream_t stream) {
  const float* x = (const float*)d_in[0];
  const float* w1 = (const float*)d_in[1];
  const float* bng = (const float*)d_in[2];
  const float* bnb = (const float*)d_in[3];
  const float* bnm = (const float*)d_in[4];
  const float* bnv = (const float*)d_in[5];
  const float* w2 = (const float*)d_in[6];
  const float* wgt = (const float*)d_in[7];
  float* out = (float*)d_out;

  char* ws = (char*)d_ws;
  const size_t xtp_bytes = (size_t)16 * 4356 * 256 * 2;    // 35,684,352
  const size_t agg_bytes = (size_t)16 * 9 * 256 * 256 * 2; // 18,874,368
  unsigned short* xTp = (unsigned short*)ws;
  unsigned short* agg = (unsigned short*)(ws + xtp_bytes);
  float* pooled = (float*)(ws + xtp_bytes + agg_bytes);
  float* att = (float*)(ws + xtp_bytes + agg_bytes + 16384);
  float* part = (float*)(ws + xtp_bytes + agg_bytes + 20480);

  transpose_kernel<<<1024, 256, 0, stream>>>(x, xTp, part);
  poolfin_kernel<<<16, 256, 0, stream>>>(part, pooled);
  attn_kernel<<<1, 256, 0, stream>>>(pooled, w1, bng, bnb, bnm, bnv, w2, att);
  agg_kernel<<<dim3(256, 2), 256, 0, stream>>>(att, wgt, agg);
  conv_kernel<<<512, 256, 0, stream>>>(xTp, agg, out);
}

// Round 10
// 130.553 us; speedup vs baseline: 1.0843x; 1.0843x over previous
//
#include <hip/hip_runtime.h>

typedef __attribute__((ext_vector_type(8))) short bf16x8;
typedef __attribute__((ext_vector_type(4))) float f32x4;

#define AS3 __attribute__((address_space(3)))
#define AS1 __attribute__((address_space(1)))

__device__ __forceinline__ unsigned short f2bf(float f) {
  unsigned u = __float_as_uint(f);
  u += 0x7fffu + ((u >> 16) & 1u);
  return (unsigned short)(u >> 16);
}
__device__ __forceinline__ float bf2f(unsigned short v) {
  return __uint_as_float((unsigned)v << 16);
}

// ---------------- kernel 1: transpose + pad + bf16 + border-zero + pool partials
__global__ void transpose_kernel(const float* __restrict__ x,
                                 unsigned short* __restrict__ xTp,
                                 float* __restrict__ part) {
  __shared__ unsigned short tb[64][258];
  __shared__ float redf[4][256];
  const int blk = blockIdx.x;
  const int b = blk >> 6, y = blk & 63;
  const int t = threadIdx.x;
  const int l = t & 63, w = t >> 6;
  const int coff = l >> 4;
  const int x4 = (l & 15) << 2;
  const float* src = x + (size_t)b * 256 * 4096 + (size_t)y * 64;
#pragma unroll 4
  for (int i = 0; i < 16; ++i) {
    const int c = w * 64 + i * 4 + coff;
    const float4 v = *reinterpret_cast<const float4*>(&src[(size_t)c * 4096 + x4]);
    tb[x4 + 0][c] = f2bf(v.x);
    tb[x4 + 1][c] = f2bf(v.y);
    tb[x4 + 2][c] = f2bf(v.z);
    tb[x4 + 3][c] = f2bf(v.w);
  }
  __syncthreads();
  unsigned short* dstb = xTp + (size_t)b * (4356 * 256);
  unsigned short* dst = dstb + ((size_t)(y + 1) * 66 + 1) * 256;
  float s0 = 0.f, s1 = 0.f, s2 = 0.f, s3 = 0.f;
#pragma unroll 4
  for (int i = 0; i < 16; ++i) {
    const int xx = w * 16 + i;
    ushort2 v0 = *(const ushort2*)&tb[xx][l * 4];
    ushort2 v1 = *(const ushort2*)&tb[xx][l * 4 + 2];
    s0 += bf2f(v0.x); s1 += bf2f(v0.y); s2 += bf2f(v1.x); s3 += bf2f(v1.y);
    ushort4 v = {v0.x, v0.y, v1.x, v1.y};
    *(ushort4*)&dst[(size_t)xx * 256 + l * 4] = v;
  }
  redf[w][l * 4 + 0] = s0;
  redf[w][l * 4 + 1] = s1;
  redf[w][l * 4 + 2] = s2;
  redf[w][l * 4 + 3] = s3;
  unsigned short* rowpad = dstb + ((size_t)(y + 1) * 66) * 256;
  rowpad[t] = 0;
  rowpad[65 * 256 + t] = 0;
  if (y == 0)
    for (int xx = 0; xx < 66; ++xx) dstb[(size_t)xx * 256 + t] = 0;
  if (y == 63)
    for (int xx = 0; xx < 66; ++xx) dstb[(size_t)(65 * 66 + xx) * 256 + t] = 0;
  __syncthreads();
  part[((size_t)(b * 64 + y)) * 256 + t] =
      redf[0][t] + redf[1][t] + redf[2][t] + redf[3][t];
}

// ---------------- kernel 1c: finish pool ----------
__global__ void poolfin_kernel(const float* __restrict__ part,
                               float* __restrict__ pooled) {
  const int b = blockIdx.x, c = threadIdx.x;
  float s = 0.f;
  for (int y = 0; y < 64; ++y) s += part[((size_t)(b * 64 + y)) * 256 + c];
  pooled[b * 256 + c] = s * (1.0f / 4096.0f);
}

// ---------------- kernel 2: attention MLP + softmax ----------------
__global__ void attn_kernel(const float* __restrict__ pooled,
                            const float* __restrict__ w1,
                            const float* __restrict__ bng,
                            const float* __restrict__ bnb,
                            const float* __restrict__ bnm,
                            const float* __restrict__ bnv,
                            const float* __restrict__ w2,
                            float* __restrict__ att) {
  __shared__ float hbuf[256];
  const int t = threadIdx.x;
  const int b = t >> 4, i = t & 15;
  float s = 0.f;
  for (int c = 0; c < 256; ++c) s += pooled[b * 256 + c] * w1[i * 256 + c];
  float h = (s - bnm[i]) * rsqrtf(bnv[i] + 1e-5f) * bng[i] + bnb[i];
  hbuf[t] = fmaxf(h, 0.f);
  __syncthreads();
  if (t < 64) {
    const int bb = t >> 2, k = t & 3;
    float l = 0.f;
    for (int j = 0; j < 16; ++j) l += hbuf[bb * 16 + j] * w2[k * 16 + j];
    float m = l;
    m = fmaxf(m, __shfl_xor(m, 1, 64));
    m = fmaxf(m, __shfl_xor(m, 2, 64));
    float e = expf(l - m);
    float sum = e;
    sum += __shfl_xor(sum, 1, 64);
    sum += __shfl_xor(sum, 2, 64);
    att[bb * 4 + k] = e / sum;
  }
}

// ---------------- kernel 3: aggregate per-sample kernels ----------------
__global__ void agg_kernel(const float* __restrict__ att,
                           const float* __restrict__ wgt,
                           unsigned short* __restrict__ agg) {
  const int o = blockIdx.x;
  const int bh = blockIdx.y;
  const int c = threadIdx.x;
  float w[4][9];
#pragma unroll
  for (int k = 0; k < 4; ++k) {
    const float* wp = wgt + ((size_t)((k << 8) + o) * 256 + c) * 9;
#pragma unroll
    for (int t = 0; t < 9; ++t) w[k][t] = wp[t];
  }
  __shared__ float attS[64];
  if (c < 64) attS[c] = att[c];
  __syncthreads();
#pragma unroll 1
  for (int b = bh * 8; b < bh * 8 + 8; ++b) {
    const float a0 = attS[b * 4 + 0], a1 = attS[b * 4 + 1];
    const float a2 = attS[b * 4 + 2], a3 = attS[b * 4 + 3];
#pragma unroll
    for (int t = 0; t < 9; ++t) {
      const float v = a0 * w[0][t] + a1 * w[1][t] + a2 * w[2][t] + a3 * w[3][t];
      agg[(((size_t)(b * 9 + t) * 256) + o) * 256 + c] = f2bf(v);
    }
  }
}

// ---------------- kernel 4: per-sample implicit-GEMM conv (bf16 MFMA) ----
// tile 256(p) x 128(cout); 4 waves (2Mx2N) of 128x64.
// A: LDS double-buffered (2x28KB), staged once per c0 under tap-0 MFMAs,
//    reused 9 taps. B: LDS ring-2 (2x8KB), stage-ahead-2 ping-pong.
// Each tap = two 16-MFMA phases, 2 barriers, counted vmcnt (never 0 in loop):
//  {vmcnt(N); bar; 8 ds_reads; 16 MFMA} {bar; stageB/stageA; 4 ds_reads; 16 MFMA}
__global__ __launch_bounds__(256, 2) void conv_kernel(
    const unsigned short* __restrict__ xTp,
    const unsigned short* __restrict__ agg,
    float* __restrict__ out) {
  // A bufs at 0 / 28672 ; B slots at 57344 + s*8192 ; total 73728 B
  __shared__ unsigned short lds[(2 * 448 * 32 + 2 * 128 * 32)];

  const int bid = blockIdx.x;
  const int b = bid & 15;   // XCD = b%8
  const int rest = bid >> 4;
  const int mt = rest >> 1;
  const int nh = rest & 1;
  const int p0 = mt << 8;
  const int rowA0 = mt * 264;

  const int tid = threadIdx.x;
  const int lane = tid & 63;
  const int wave = tid >> 6;
  const int wm = wave >> 1;
  const int wn = wave & 1;

  const int srow = tid >> 2;
  const int scol = ((tid & 3) ^ ((tid >> 3) & 3)) << 3;
  const int sdst = srow * 64 + (tid & 3) * 16;

  const unsigned short* xbs =
      xTp + (size_t)b * (4356 * 256) + (size_t)rowA0 * 256 + scol;
  const unsigned short* aggs =
      agg + ((size_t)(b * 9) * 256 + nh * 128 + srow) * 256 + scol;
  AS3 char* ldsA3 = (AS3 char*)lds;
  AS3 char* ldsB3 = ((AS3 char*)lds) + 57344;

  auto stageA = [&](int c0s, int bufo) {
#pragma unroll
    for (int i = 0; i < 7; ++i) {
      const int h = srow + (i << 6);
      const int hs = h > 395 ? 395 : h;
      __builtin_amdgcn_global_load_lds(
          (const AS1 void*)(xbs + (size_t)hs * 256 + c0s * 32),
          (AS3 void*)(ldsA3 + bufo + sdst + (i << 12)), 16, 0, 0);
    }
  };
  auto stageB = [&](int c02, int tap2, int slot) {
#pragma unroll
    for (int j = 0; j < 2; ++j) {
      __builtin_amdgcn_global_load_lds(
          (const AS1 void*)(aggs + tap2 * 65536 + (j << 14) + c02 * 32),
          (AS3 void*)(ldsB3 + slot * 8192 + sdst + (j << 12)), 16, 0, 0);
    }
  };

  const int l15 = lane & 15;
  const int lhi = lane >> 4;
  const int hb0 = wm * 132 + l15;
  const int rslotB = (lhi ^ ((l15 >> 1) & 3)) << 4;
  int boffs[4];
#pragma unroll
  for (int n = 0; n < 4; ++n)
    boffs[n] = 57344 + (wn * 64 + n * 16 + l15) * 64 + rslotB;

  f32x4 acc[8][4];
#pragma unroll
  for (int m = 0; m < 8; ++m)
#pragma unroll
    for (int n = 0; n < 4; ++n) acc[m][n] = (f32x4){0.f, 0.f, 0.f, 0.f};

#define RDA(reg, mm, tt)                                                      \
  {                                                                           \
    const int h_ = hb0 + (((mm) >> 2) + (tt) / 3) * 66 + ((mm)&3) * 16 + (tt) % 3; \
    reg = *(const bf16x8*)((const char*)lds + bufb + h_ * 64 +                \
                           ((lhi ^ ((h_ >> 1) & 3)) << 4));                   \
  }
#define RDB(reg, nn, tt)                                                      \
  reg = *(const bf16x8*)((const char*)lds + (((c0 + (tt)) & 1) << 13) + boffs[nn]);
#define MF4(areg, ii)                                                         \
  acc[ii][0] = __builtin_amdgcn_mfma_f32_16x16x32_bf16(areg, b0, acc[ii][0], 0, 0, 0); \
  acc[ii][1] = __builtin_amdgcn_mfma_f32_16x16x32_bf16(areg, b1, acc[ii][1], 0, 0, 0); \
  acc[ii][2] = __builtin_amdgcn_mfma_f32_16x16x32_bf16(areg, b2, acc[ii][2], 0, 0, 0); \
  acc[ii][3] = __builtin_amdgcn_mfma_f32_16x16x32_bf16(areg, b3, acc[ii][3], 0, 0, 0);
#define STB(tt)                                                               \
  {                                                                           \
    int c02_ = c0 + ((tt) + 2) / 9, tap2_ = ((tt) + 2) % 9;                   \
    if (c02_ > 7) { c02_ = 7; tap2_ = 8; }                                    \
    stageB(c02_, tap2_, (c0 + (tt)) & 1);                                     \
  }
// Two-phase tap. vmcnt literal VMC: "2" steady, "9" for the 2 taps after
// the 7-load A stage (in-order queue: waiting to <=N covers B(g) landing).
#define TAPBODY(tt, VMC)                                                      \
  {                                                                           \
    asm volatile("s_waitcnt vmcnt(" VMC ")" ::: "memory");                    \
    __builtin_amdgcn_s_barrier();                                             \
    __builtin_amdgcn_sched_barrier(0);                                        \
    bf16x8 a0, a1, a2, a3, a4, a5, a6, a7, b0, b1, b2, b3;                    \
    RDA(a0, 0, tt) RDA(a1, 1, tt) RDA(a2, 2, tt) RDA(a3, 3, tt)               \
    RDB(b0, 0, tt) RDB(b1, 1, tt) RDB(b2, 2, tt) RDB(b3, 3, tt)               \
    __builtin_amdgcn_s_setprio(1);                                            \
    MF4(a0, 0) MF4(a1, 1) MF4(a2, 2) MF4(a3, 3)                               \
    __builtin_amdgcn_s_setprio(0);                                            \
    __builtin_amdgcn_s_barrier();  /* all waves read B(g): slot reusable */   \
    __builtin_amdgcn_sched_barrier(0);                                        \
    STB(tt);                                                                  \
    if ((tt) == 0) stageA(c0 < 7 ? c0 + 1 : 7, bufb ^ 28672);                 \
    RDA(a4, 4, tt) RDA(a5, 5, tt) RDA(a6, 6, tt) RDA(a7, 7, tt)               \
    __builtin_amdgcn_s_setprio(1);                                            \
    MF4(a4, 4) MF4(a5, 5) MF4(a6, 6) MF4(a7, 7)                               \
    __builtin_amdgcn_s_setprio(0);                                            \
  }

  // prologue: prime A(0) and B(g=0,1); single full drain outside the loop
  stageA(0, 0);
  stageB(0, 0, 0);
  stageB(0, 1, 1);
  asm volatile("s_waitcnt vmcnt(0)" ::: "memory");
  __builtin_amdgcn_s_barrier();

#pragma unroll 1
  for (int c0 = 0; c0 < 8; ++c0) {
    const int bufb = (c0 & 1) * 28672;
    TAPBODY(0, "2")
    TAPBODY(1, "9")
    TAPBODY(2, "9")
    TAPBODY(3, "2")
    TAPBODY(4, "2")
    TAPBODY(5, "2")
    TAPBODY(6, "2")
    TAPBODY(7, "2")
    TAPBODY(8, "2")
  }

  // epilogue: D row=(lane>>4)*4+reg is p, col=lane&15 is cout
#pragma unroll
  for (int m = 0; m < 8; ++m) {
    const int p = p0 + wm * 128 + (m >> 2) * 64 + (m & 3) * 16 + (lhi << 2);
#pragma unroll
    for (int n = 0; n < 4; ++n) {
      const int co = nh * 128 + wn * 64 + n * 16 + l15;
      float* dst = out + ((size_t)(b * 256 + co) << 12) + p;
      *reinterpret_cast<f32x4*>(dst) = acc[m][n];
    }
  }
#undef RDA
#undef RDB
#undef MF4
#undef STB
#undef TAPBODY
}

extern "C" void kernel_launch(void* const* d_in, const int* in_sizes, int n_in,
                              void* d_out, int out_size, void* d_ws, size_t ws_size,
                              hipStream_t stream) {
  const float* x = (const float*)d_in[0];
  const float* w1 = (const float*)d_in[1];
  const float* bng = (const float*)d_in[2];
  const float* bnb = (const float*)d_in[3];
  const float* bnm = (const float*)d_in[4];
  const float* bnv = (const float*)d_in[5];
  const float* w2 = (const float*)d_in[6];
  const float* wgt = (const float*)d_in[7];
  float* out = (float*)d_out;

  char* ws = (char*)d_ws;
  const size_t xtp_bytes = (size_t)16 * 4356 * 256 * 2;    // 35,684,352
  const size_t agg_bytes = (size_t)16 * 9 * 256 * 256 * 2; // 18,874,368
  unsigned short* xTp = (unsigned short*)ws;
  unsigned short* agg = (unsigned short*)(ws + xtp_bytes);
  float* pooled = (float*)(ws + xtp_bytes + agg_bytes);
  float* att = (float*)(ws + xtp_bytes + agg_bytes + 16384);
  float* part = (float*)(ws + xtp_bytes + agg_bytes + 20480);

  transpose_kernel<<<1024, 256, 0, stream>>>(x, xTp, part);
  poolfin_kernel<<<16, 256, 0, stream>>>(part, pooled);
  attn_kernel<<<1, 256, 0, stream>>>(pooled, w1, bng, bnb, bnm, bnv, w2, att);
  agg_kernel<<<dim3(256, 2), 256, 0, stream>>>(att, wgt, agg);
  conv_kernel<<<512, 256, 0, stream>>>(xTp, agg, out);
}

// Round 11
// 113.405 us; speedup vs baseline: 1.2482x; 1.1512x over previous
//
#include <hip/hip_runtime.h>

typedef __attribute__((ext_vector_type(8))) short bf16x8;
typedef __attribute__((ext_vector_type(4))) float f32x4;

#define AS3 __attribute__((address_space(3)))
#define AS1 __attribute__((address_space(1)))

__device__ __forceinline__ unsigned short f2bf(float f) {
  unsigned u = __float_as_uint(f);
  u += 0x7fffu + ((u >> 16) & 1u);
  return (unsigned short)(u >> 16);
}
__device__ __forceinline__ float bf2f(unsigned short v) {
  return __uint_as_float((unsigned)v << 16);
}

// ---------------- kernel 1: transpose + pad + bf16 + border-zero + pool partials
__global__ void transpose_kernel(const float* __restrict__ x,
                                 unsigned short* __restrict__ xTp,
                                 float* __restrict__ part) {
  __shared__ unsigned short tb[64][258];
  __shared__ float redf[4][256];
  const int blk = blockIdx.x;
  const int b = blk >> 6, y = blk & 63;
  const int t = threadIdx.x;
  const int l = t & 63, w = t >> 6;
  const int coff = l >> 4;
  const int x4 = (l & 15) << 2;
  const float* src = x + (size_t)b * 256 * 4096 + (size_t)y * 64;
#pragma unroll 4
  for (int i = 0; i < 16; ++i) {
    const int c = w * 64 + i * 4 + coff;
    const float4 v = *reinterpret_cast<const float4*>(&src[(size_t)c * 4096 + x4]);
    tb[x4 + 0][c] = f2bf(v.x);
    tb[x4 + 1][c] = f2bf(v.y);
    tb[x4 + 2][c] = f2bf(v.z);
    tb[x4 + 3][c] = f2bf(v.w);
  }
  __syncthreads();
  unsigned short* dstb = xTp + (size_t)b * (4356 * 256);
  unsigned short* dst = dstb + ((size_t)(y + 1) * 66 + 1) * 256;
  float s0 = 0.f, s1 = 0.f, s2 = 0.f, s3 = 0.f;
#pragma unroll 4
  for (int i = 0; i < 16; ++i) {
    const int xx = w * 16 + i;
    ushort2 v0 = *(const ushort2*)&tb[xx][l * 4];
    ushort2 v1 = *(const ushort2*)&tb[xx][l * 4 + 2];
    s0 += bf2f(v0.x); s1 += bf2f(v0.y); s2 += bf2f(v1.x); s3 += bf2f(v1.y);
    ushort4 v = {v0.x, v0.y, v1.x, v1.y};
    *(ushort4*)&dst[(size_t)xx * 256 + l * 4] = v;
  }
  redf[w][l * 4 + 0] = s0;
  redf[w][l * 4 + 1] = s1;
  redf[w][l * 4 + 2] = s2;
  redf[w][l * 4 + 3] = s3;
  unsigned short* rowpad = dstb + ((size_t)(y + 1) * 66) * 256;
  rowpad[t] = 0;
  rowpad[65 * 256 + t] = 0;
  if (y == 0)
    for (int xx = 0; xx < 66; ++xx) dstb[(size_t)xx * 256 + t] = 0;
  if (y == 63)
    for (int xx = 0; xx < 66; ++xx) dstb[(size_t)(65 * 66 + xx) * 256 + t] = 0;
  __syncthreads();
  part[((size_t)(b * 64 + y)) * 256 + t] =
      redf[0][t] + redf[1][t] + redf[2][t] + redf[3][t];
}

// ---------------- kernel 1c: finish pool ----------
__global__ void poolfin_kernel(const float* __restrict__ part,
                               float* __restrict__ pooled) {
  const int b = blockIdx.x, c = threadIdx.x;
  float s = 0.f;
  for (int y = 0; y < 64; ++y) s += part[((size_t)(b * 64 + y)) * 256 + c];
  pooled[b * 256 + c] = s * (1.0f / 4096.0f);
}

// ---------------- kernel 2: attention MLP + softmax ----------------
__global__ void attn_kernel(const float* __restrict__ pooled,
                            const float* __restrict__ w1,
                            const float* __restrict__ bng,
                            const float* __restrict__ bnb,
                            const float* __restrict__ bnm,
                            const float* __restrict__ bnv,
                            const float* __restrict__ w2,
                            float* __restrict__ att) {
  __shared__ float hbuf[256];
  const int t = threadIdx.x;
  const int b = t >> 4, i = t & 15;
  float s = 0.f;
  for (int c = 0; c < 256; ++c) s += pooled[b * 256 + c] * w1[i * 256 + c];
  float h = (s - bnm[i]) * rsqrtf(bnv[i] + 1e-5f) * bng[i] + bnb[i];
  hbuf[t] = fmaxf(h, 0.f);
  __syncthreads();
  if (t < 64) {
    const int bb = t >> 2, k = t & 3;
    float l = 0.f;
    for (int j = 0; j < 16; ++j) l += hbuf[bb * 16 + j] * w2[k * 16 + j];
    float m = l;
    m = fmaxf(m, __shfl_xor(m, 1, 64));
    m = fmaxf(m, __shfl_xor(m, 2, 64));
    float e = expf(l - m);
    float sum = e;
    sum += __shfl_xor(sum, 1, 64);
    sum += __shfl_xor(sum, 2, 64);
    att[bb * 4 + k] = e / sum;
  }
}

// ---------------- kernel 3: aggregate per-sample kernels ----------------
__global__ void agg_kernel(const float* __restrict__ att,
                           const float* __restrict__ wgt,
                           unsigned short* __restrict__ agg) {
  const int o = blockIdx.x;
  const int bh = blockIdx.y;
  const int c = threadIdx.x;
  float w[4][9];
#pragma unroll
  for (int k = 0; k < 4; ++k) {
    const float* wp = wgt + ((size_t)((k << 8) + o) * 256 + c) * 9;
#pragma unroll
    for (int t = 0; t < 9; ++t) w[k][t] = wp[t];
  }
  __shared__ float attS[64];
  if (c < 64) attS[c] = att[c];
  __syncthreads();
#pragma unroll 1
  for (int b = bh * 8; b < bh * 8 + 8; ++b) {
    const float a0 = attS[b * 4 + 0], a1 = attS[b * 4 + 1];
    const float a2 = attS[b * 4 + 2], a3 = attS[b * 4 + 3];
#pragma unroll
    for (int t = 0; t < 9; ++t) {
      const float v = a0 * w[0][t] + a1 * w[1][t] + a2 * w[2][t] + a3 * w[3][t];
      agg[(((size_t)(b * 9 + t) * 256) + o) * 256 + c] = f2bf(v);
    }
  }
}

// ---------------- kernel 4: per-sample implicit-GEMM conv (bf16 MFMA) ----
// tile 256(p) x 128(cout); 4 waves (2Mx2N) of 128x64.
// m201-style pipeline: every ds_read is issued ONE PHASE before its MFMA.
// A: LDS dbuf (2x28KB), staged via 1-load-per-tap chunks (uniform stream).
// B: LDS ring-3 (3x8KB), staged 3 taps ahead. Uniform 3 loads/tap ->
// constant vmcnt(3) gate at each tap ph0; loads never drain to 0.
// 72 taps = 36 pairs -> compile-time register parity (A0/A1/B0/B1).
__global__ __launch_bounds__(256, 2) void conv_kernel(
    const unsigned short* __restrict__ xTp,
    const unsigned short* __restrict__ agg,
    float* __restrict__ out) {
  // A buf0 @0, buf1 @28672 ; B slots @57344 + s*8192 ; total 81920 B
  __shared__ unsigned short lds[40960];

  const int bid = blockIdx.x;
  const int b = bid & 15;   // XCD = b%8
  const int rest = bid >> 4;
  const int mt = rest >> 1;
  const int nh = rest & 1;
  const int p0 = mt << 8;
  const int rowA0 = mt * 264;

  const int tid = threadIdx.x;
  const int lane = tid & 63;
  const int wave = tid >> 6;
  const int wm = wave >> 1;
  const int wn = wave & 1;

  const int srow = tid >> 2;
  const int scol = ((tid & 3) ^ ((tid >> 3) & 3)) << 3;
  const int sdst = srow * 64 + (tid & 3) * 16;

  const unsigned short* xbs =
      xTp + (size_t)b * (4356 * 256) + (size_t)rowA0 * 256 + scol;
  const unsigned short* aggs =
      agg + ((size_t)(b * 9) * 256 + nh * 128 + srow) * 256 + scol;
  AS3 char* ldsA3 = (AS3 char*)lds;
  AS3 char* ldsB3 = ((AS3 char*)lds) + 57344;

  auto stageA = [&](int c0s, int bufo) {
#pragma unroll
    for (int i = 0; i < 7; ++i) {
      const int h = srow + (i << 6);
      const int hs = h > 395 ? 395 : h;
      __builtin_amdgcn_global_load_lds(
          (const AS1 void*)(xbs + (size_t)hs * 256 + c0s * 32),
          (AS3 void*)(ldsA3 + bufo + sdst + (i << 12)), 16, 0, 0);
    }
  };
  auto stageB = [&](int c02, int tap2, int slotb) {
#pragma unroll
    for (int j = 0; j < 2; ++j) {
      __builtin_amdgcn_global_load_lds(
          (const AS1 void*)(aggs + tap2 * 65536 + (j << 14) + c02 * 32),
          (AS3 void*)(ldsB3 + slotb + sdst + (j << 12)), 16, 0, 0);
    }
  };
  // one A-chunk (64 tile-rows) of A(c0cur+1) into the other buffer
  auto chunkA = [&](int tapc, int c0cur) {
    const int i = tapc > 6 ? 6 : tapc;  // taps 7,8: idempotent dummy re-stage
    const int c0s = c0cur < 7 ? c0cur + 1 : 7;
    const int bufo = ((c0cur + 1) & 1) * 28672;
    const int h = srow + (i << 6);
    const int hs = h > 395 ? 395 : h;
    __builtin_amdgcn_global_load_lds(
        (const AS1 void*)(xbs + (size_t)hs * 256 + c0s * 32),
        (AS3 void*)(ldsA3 + bufo + sdst + (i << 12)), 16, 0, 0);
  };

  const int l15 = lane & 15;
  const int lhi = lane >> 4;
  const int hb0 = wm * 132 + l15;
  const int rslotB = (lhi ^ ((l15 >> 1) & 3)) << 4;
  int bo[4];
#pragma unroll
  for (int n = 0; n < 4; ++n)
    bo[n] = (wn * 64 + n * 16 + l15) * 64 + rslotB;

  f32x4 acc[8][4];
#pragma unroll
  for (int m = 0; m < 8; ++m)
#pragma unroll
    for (int n = 0; n < 4; ++n) acc[m][n] = (f32x4){0.f, 0.f, 0.f, 0.f};

#define RDA4(DST, HB, BUF, HOFF)                                              \
  _Pragma("unroll") for (int jj = 0; jj < 4; ++jj) {                          \
    const int h_ = (HB) + (HOFF) + jj * 16;                                   \
    DST[jj] = *(const bf16x8*)((const char*)lds + (BUF) + h_ * 64 +           \
                               ((lhi ^ ((h_ >> 1) & 3)) << 4));               \
  }
#define RDB4(DST, SLOTB)                                                      \
  _Pragma("unroll") for (int nn = 0; nn < 4; ++nn) DST[nn] =                  \
      *(const bf16x8*)((const char*)lds + 57344 + (SLOTB) + bo[nn]);
#define MFMA16(AX, BX, R)                                                     \
  _Pragma("unroll") for (int mm = 0; mm < 4; ++mm)                            \
  _Pragma("unroll") for (int nn = 0; nn < 4; ++nn)                            \
      acc[(R) + mm][nn] = __builtin_amdgcn_mfma_f32_16x16x32_bf16(            \
          AX[mm], BX[nn], acc[(R) + mm][nn], 0, 0, 0);

  bf16x8 A0[4], A1[4], B0[4], B1[4];

  // prologue: A(0) full, B(0..2); single drain; prime tap0 frags
  stageA(0, 0);
  stageB(0, 0, 0);
  stageB(0, 1, 8192);
  stageB(0, 2, 16384);
  asm volatile("s_waitcnt vmcnt(0)" ::: "memory");
  __builtin_amdgcn_s_barrier();
  __builtin_amdgcn_sched_barrier(0);
  RDA4(A0, hb0, 0, 0);
  RDB4(B0, 0);

  int ks = 0;
#pragma unroll 1
  for (int it = 0; it < 36; ++it) {
    const int ksE = ks, ksO = ks + 1;
    const int c0E = (ksE * 57) >> 9, tapE = ksE - c0E * 9;
    const int c0O = (ksO * 57) >> 9, tapO = ksO - c0O * 9;
    int ksN = ks + 2;
    int c0N = (ksN * 57) >> 9, tapN = ksN - c0N * 9;
    if (ksN > 71) { c0N = 7; tapN = 8; }
    int ksP = ks + 3;
    int c0P = (ksP * 57) >> 9, tapP = ksP - c0P * 9;
    if (ksP > 71) { c0P = 7; tapP = 8; }
    int ksQ = ks + 4;
    int c0Q = (ksQ * 57) >> 9, tapQ = ksQ - c0Q * 9;
    if (ksQ > 71) { c0Q = 7; tapQ = 8; }
    const int bufE = (c0E & 1) * 28672;
    const int bufO = (c0O & 1) * 28672;
    const int bufN = (c0N & 1) * 28672;
    const int dyE = (tapE * 171) >> 9, dxE = tapE - dyE * 3;
    const int dyO = (tapO * 171) >> 9, dxO = tapO - dyO * 3;
    const int dyN = (tapN * 171) >> 9, dxN = tapN - dyN * 3;
    const int hbE = hb0 + dyE * 66 + dxE;
    const int hbO = hb0 + dyO * 66 + dxO;
    const int hbN = hb0 + dyN * 66 + dxN;
    const int slotO = (ksO % 3) * 8192;  // B(O) lives in slot O%3
    const int slotN = (ksN % 3) * 8192;  // B(N) (raw index; clamped src ok)
    const int slotSE = (ksE % 3) * 8192; // STB@E target: (ksE+3)%3 == ksE%3
    const int slotSO = (ksO % 3) * 8192;

    // ---------- E.ph0 : MFMA tap E rows 0-3 ; read a4-7(E) ----------
    asm volatile("s_waitcnt vmcnt(3)" ::: "memory");
    __builtin_amdgcn_s_barrier();
    __builtin_amdgcn_sched_barrier(0);
    RDA4(A1, hbE, bufE, 66);
    __builtin_amdgcn_sched_barrier(0);
    __builtin_amdgcn_s_setprio(1);
    MFMA16(A0, B0, 0);
    __builtin_amdgcn_s_setprio(0);
    // ---------- E.ph1 : MFMA tap E rows 4-7 ; read a0-3(O), B(O); stage ----
    __builtin_amdgcn_s_barrier();
    __builtin_amdgcn_sched_barrier(0);
    RDA4(A0, hbO, bufO, 0);
    RDB4(B1, slotO);
    stageB(c0P, tapP, slotSE);  // B(E+3)
    chunkA(tapE, c0E);
    __builtin_amdgcn_sched_barrier(0);
    __builtin_amdgcn_s_setprio(1);
    MFMA16(A1, B0, 4);
    __builtin_amdgcn_s_setprio(0);
    // ---------- O.ph0 : MFMA tap O rows 0-3 ; read a4-7(O) ----------
    asm volatile("s_waitcnt vmcnt(3)" ::: "memory");
    __builtin_amdgcn_s_barrier();
    __builtin_amdgcn_sched_barrier(0);
    RDA4(A1, hbO, bufO, 66);
    __builtin_amdgcn_sched_barrier(0);
    __builtin_amdgcn_s_setprio(1);
    MFMA16(A0, B1, 0);
    __builtin_amdgcn_s_setprio(0);
    // ---------- O.ph1 : MFMA tap O rows 4-7 ; read a0-3(N), B(N); stage ----
    __builtin_amdgcn_s_barrier();
    __builtin_amdgcn_sched_barrier(0);
    RDA4(A0, hbN, bufN, 0);
    RDB4(B0, slotN);
    stageB(c0Q, tapQ, slotSO);  // B(O+3)
    chunkA(tapO, c0O);
    __builtin_amdgcn_sched_barrier(0);
    __builtin_amdgcn_s_setprio(1);
    MFMA16(A1, B1, 4);
    __builtin_amdgcn_s_setprio(0);
    ks += 2;
  }

  // epilogue: D row=(lane>>4)*4+reg is p, col=lane&15 is cout
#pragma unroll
  for (int m = 0; m < 8; ++m) {
    const int p = p0 + wm * 128 + (m >> 2) * 64 + (m & 3) * 16 + (lhi << 2);
#pragma unroll
    for (int n = 0; n < 4; ++n) {
      const int co = nh * 128 + wn * 64 + n * 16 + l15;
      float* dst = out + ((size_t)(b * 256 + co) << 12) + p;
      *reinterpret_cast<f32x4*>(dst) = acc[m][n];
    }
  }
#undef RDA4
#undef RDB4
#undef MFMA16
}

extern "C" void kernel_launch(void* const* d_in, const int* in_sizes, int n_in,
                              void* d_out, int out_size, void* d_ws, size_t ws_size,
                              hipStream_t stream) {
  const float* x = (const float*)d_in[0];
  const float* w1 = (const float*)d_in[1];
  const float* bng = (const float*)d_in[2];
  const float* bnb = (const float*)d_in[3];
  const float* bnm = (const float*)d_in[4];
  const float* bnv = (const float*)d_in[5];
  const float* w2 = (const float*)d_in[6];
  const float* wgt = (const float*)d_in[7];
  float* out = (float*)d_out;

  char* ws = (char*)d_ws;
  const size_t xtp_bytes = (size_t)16 * 4356 * 256 * 2;    // 35,684,352
  const size_t agg_bytes = (size_t)16 * 9 * 256 * 256 * 2; // 18,874,368
  unsigned short* xTp = (unsigned short*)ws;
  unsigned short* agg = (unsigned short*)(ws + xtp_bytes);
  float* pooled = (float*)(ws + xtp_bytes + agg_bytes);
  float* att = (float*)(ws + xtp_bytes + agg_bytes + 16384);
  float* part = (float*)(ws + xtp_bytes + agg_bytes + 20480);

  transpose_kernel<<<1024, 256, 0, stream>>>(x, xTp, part);
  poolfin_kernel<<<16, 256, 0, stream>>>(part, pooled);
  attn_kernel<<<1, 256, 0, stream>>>(pooled, w1, bng, bnb, bnm, bnv, w2, att);
  agg_kernel<<<dim3(256, 2), 256, 0, stream>>>(att, wgt, agg);
  conv_kernel<<<512, 256, 0, stream>>>(xTp, agg, out);
}

// Round 12
// 110.708 us; speedup vs baseline: 1.2787x; 1.0244x over previous
//
#include <hip/hip_runtime.h>

typedef __attribute__((ext_vector_type(8))) short bf16x8;
typedef __attribute__((ext_vector_type(4))) float f32x4;

#define AS3 __attribute__((address_space(3)))
#define AS1 __attribute__((address_space(1)))

__device__ __forceinline__ unsigned short f2bf(float f) {
  unsigned u = __float_as_uint(f);
  u += 0x7fffu + ((u >> 16) & 1u);
  return (unsigned short)(u >> 16);
}
__device__ __forceinline__ float bf2f(unsigned short v) {
  return __uint_as_float((unsigned)v << 16);
}

// ---------------- kernel 1: transpose + pad + bf16 + border-zero + pool partials
__global__ void transpose_kernel(const float* __restrict__ x,
                                 unsigned short* __restrict__ xTp,
                                 float* __restrict__ part) {
  __shared__ unsigned short tb[64][258];
  __shared__ float redf[4][256];
  const int blk = blockIdx.x;
  const int b = blk >> 6, y = blk & 63;
  const int t = threadIdx.x;
  const int l = t & 63, w = t >> 6;
  const int coff = l >> 4;
  const int x4 = (l & 15) << 2;
  const float* src = x + (size_t)b * 256 * 4096 + (size_t)y * 64;
#pragma unroll 4
  for (int i = 0; i < 16; ++i) {
    const int c = w * 64 + i * 4 + coff;
    const float4 v = *reinterpret_cast<const float4*>(&src[(size_t)c * 4096 + x4]);
    tb[x4 + 0][c] = f2bf(v.x);
    tb[x4 + 1][c] = f2bf(v.y);
    tb[x4 + 2][c] = f2bf(v.z);
    tb[x4 + 3][c] = f2bf(v.w);
  }
  __syncthreads();
  unsigned short* dstb = xTp + (size_t)b * (4356 * 256);
  unsigned short* dst = dstb + ((size_t)(y + 1) * 66 + 1) * 256;
  float s0 = 0.f, s1 = 0.f, s2 = 0.f, s3 = 0.f;
#pragma unroll 4
  for (int i = 0; i < 16; ++i) {
    const int xx = w * 16 + i;
    ushort2 v0 = *(const ushort2*)&tb[xx][l * 4];
    ushort2 v1 = *(const ushort2*)&tb[xx][l * 4 + 2];
    s0 += bf2f(v0.x); s1 += bf2f(v0.y); s2 += bf2f(v1.x); s3 += bf2f(v1.y);
    ushort4 v = {v0.x, v0.y, v1.x, v1.y};
    *(ushort4*)&dst[(size_t)xx * 256 + l * 4] = v;
  }
  redf[w][l * 4 + 0] = s0;
  redf[w][l * 4 + 1] = s1;
  redf[w][l * 4 + 2] = s2;
  redf[w][l * 4 + 3] = s3;
  unsigned short* rowpad = dstb + ((size_t)(y + 1) * 66) * 256;
  rowpad[t] = 0;
  rowpad[65 * 256 + t] = 0;
  if (y == 0)
    for (int xx = 0; xx < 66; ++xx) dstb[(size_t)xx * 256 + t] = 0;
  if (y == 63)
    for (int xx = 0; xx < 66; ++xx) dstb[(size_t)(65 * 66 + xx) * 256 + t] = 0;
  __syncthreads();
  part[((size_t)(b * 64 + y)) * 256 + t] =
      redf[0][t] + redf[1][t] + redf[2][t] + redf[3][t];
}

// ---------------- kernel 1c: finish pool ----------
__global__ void poolfin_kernel(const float* __restrict__ part,
                               float* __restrict__ pooled) {
  const int b = blockIdx.x, c = threadIdx.x;
  float s = 0.f;
  for (int y = 0; y < 64; ++y) s += part[((size_t)(b * 64 + y)) * 256 + c];
  pooled[b * 256 + c] = s * (1.0f / 4096.0f);
}

// ---------------- kernel 2: attention MLP + softmax ----------------
__global__ void attn_kernel(const float* __restrict__ pooled,
                            const float* __restrict__ w1,
                            const float* __restrict__ bng,
                            const float* __restrict__ bnb,
                            const float* __restrict__ bnm,
                            const float* __restrict__ bnv,
                            const float* __restrict__ w2,
                            float* __restrict__ att) {
  __shared__ float hbuf[256];
  const int t = threadIdx.x;
  const int b = t >> 4, i = t & 15;
  float s = 0.f;
  for (int c = 0; c < 256; ++c) s += pooled[b * 256 + c] * w1[i * 256 + c];
  float h = (s - bnm[i]) * rsqrtf(bnv[i] + 1e-5f) * bng[i] + bnb[i];
  hbuf[t] = fmaxf(h, 0.f);
  __syncthreads();
  if (t < 64) {
    const int bb = t >> 2, k = t & 3;
    float l = 0.f;
    for (int j = 0; j < 16; ++j) l += hbuf[bb * 16 + j] * w2[k * 16 + j];
    float m = l;
    m = fmaxf(m, __shfl_xor(m, 1, 64));
    m = fmaxf(m, __shfl_xor(m, 2, 64));
    float e = expf(l - m);
    float sum = e;
    sum += __shfl_xor(sum, 1, 64);
    sum += __shfl_xor(sum, 2, 64);
    att[bb * 4 + k] = e / sum;
  }
}

// ---------------- kernel 3: aggregate per-sample kernels ----------------
__global__ void agg_kernel(const float* __restrict__ att,
                           const float* __restrict__ wgt,
                           unsigned short* __restrict__ agg) {
  const int o = blockIdx.x;
  const int bh = blockIdx.y;
  const int c = threadIdx.x;
  float w[4][9];
#pragma unroll
  for (int k = 0; k < 4; ++k) {
    const float* wp = wgt + ((size_t)((k << 8) + o) * 256 + c) * 9;
#pragma unroll
    for (int t = 0; t < 9; ++t) w[k][t] = wp[t];
  }
  __shared__ float attS[64];
  if (c < 64) attS[c] = att[c];
  __syncthreads();
#pragma unroll 1
  for (int b = bh * 8; b < bh * 8 + 8; ++b) {
    const float a0 = attS[b * 4 + 0], a1 = attS[b * 4 + 1];
    const float a2 = attS[b * 4 + 2], a3 = attS[b * 4 + 3];
#pragma unroll
    for (int t = 0; t < 9; ++t) {
      const float v = a0 * w[0][t] + a1 * w[1][t] + a2 * w[2][t] + a3 * w[3][t];
      agg[(((size_t)(b * 9 + t) * 256) + o) * 256 + c] = f2bf(v);
    }
  }
}

// ---------------- kernel 4: per-sample implicit-GEMM conv (bf16 MFMA) ----
// EXACT R6 structure (proven 70us): tile 256x128, 4 waves (2Mx2N) of 128x64,
// A-halo staged once per c0 (reused 9 taps), B ring-4 depth-2 vmcnt(2),
// 1 barrier/tap.  NEW (single variable): anti-phase skew — co-CU block pair
// (bid, bid+256) offset by ~1000 cyc so one block's MFMA-issue phase overlays
// the other's LDS-read phase (breaks the measured serial sum 1242+1152 cyc).
__global__ __launch_bounds__(256, 2) void conv_kernel(
    const unsigned short* __restrict__ xTp,
    const unsigned short* __restrict__ agg,
    float* __restrict__ out) {
  __shared__ unsigned short lds[448 * 32 + 4 * 128 * 32];  // 61440 B
  AS3 char* ldsA3 = (AS3 char*)lds;
  AS3 char* ldsB3 = ((AS3 char*)lds) + 28672;

  const int bid = blockIdx.x;

  // anti-phase skew: second half of grid (co-CU partners) delays ~1024 cyc
  if ((bid >> 8) & 1) {
    __builtin_amdgcn_s_sleep(8);
    __builtin_amdgcn_s_sleep(8);
  }

  const int b = bid & 15;   // XCD = b%8
  const int rest = bid >> 4;
  const int mt = rest >> 1;
  const int nh = rest & 1;
  const int p0 = mt << 8;
  const int rowA0 = mt * 264;

  const int tid = threadIdx.x;
  const int lane = tid & 63;
  const int wave = tid >> 6;
  const int wm = wave >> 1;
  const int wn = wave & 1;

  const int srow = tid >> 2;
  const int scol = ((tid & 3) ^ ((tid >> 3) & 3)) << 3;
  const int sdst = srow * 64 + (tid & 3) * 16;

  const unsigned short* xbs =
      xTp + (size_t)b * (4356 * 256) + (size_t)rowA0 * 256 + scol;
  const unsigned short* aggs =
      agg + ((size_t)(b * 9) * 256 + nh * 128 + srow) * 256 + scol;

  auto stageA = [&](int c0) {
#pragma unroll
    for (int i = 0; i < 7; ++i) {
      const int h = srow + (i << 6);
      const int hs = h > 395 ? 395 : h;
      __builtin_amdgcn_global_load_lds(
          (const AS1 void*)(xbs + (size_t)hs * 256 + c0 * 32),
          (AS3 void*)(ldsA3 + sdst + (i << 12)), 16, 0, 0);
    }
  };
  auto stageB = [&](int c02, int tap2, int slot) {
#pragma unroll
    for (int j = 0; j < 2; ++j) {
      __builtin_amdgcn_global_load_lds(
          (const AS1 void*)(aggs + tap2 * 65536 + (j << 14) + c02 * 32),
          (AS3 void*)(ldsB3 + slot * 8192 + sdst + (j << 12)), 16, 0, 0);
    }
  };

  const int l15 = lane & 15;
  const int lhi = lane >> 4;
  const int hb0 = wm * 132 + l15;
  const int rslotB = (lhi ^ ((l15 >> 1) & 3)) << 4;
  int boffs[4];
#pragma unroll
  for (int n = 0; n < 4; ++n)
    boffs[n] = 28672 + (wn * 64 + n * 16 + l15) * 64 + rslotB;

  f32x4 acc[8][4];
#pragma unroll
  for (int m = 0; m < 8; ++m)
#pragma unroll
    for (int n = 0; n < 4; ++n) acc[m][n] = (f32x4){0.f, 0.f, 0.f, 0.f};

  stageB(0, 0, 0);
  stageB(0, 1, 1);

#pragma unroll 1
  for (int c0 = 0; c0 < 8; ++c0) {
    __builtin_amdgcn_s_barrier();  // all waves done reading A(c0-1)
    stageA(c0);
    asm volatile("s_waitcnt vmcnt(0)" ::: "memory");
    __builtin_amdgcn_s_barrier();
#pragma unroll
    for (int tap = 0; tap < 9; ++tap) {
      if (tap != 0) {
        asm volatile("s_waitcnt vmcnt(2)" ::: "memory");  // B[tap] landed
        __builtin_amdgcn_s_barrier();
      }
      __builtin_amdgcn_sched_barrier(0);
      const int dy = tap / 3, dx = tap % 3;
      const int slotR = (c0 + tap) & 3;
      bf16x8 af[8], bfr[4];
#pragma unroll
      for (int m = 0; m < 8; ++m) {
        const int h = hb0 + ((m >> 2) + dy) * 66 + (m & 3) * 16 + dx;
        const int ab = h * 64 + ((lhi ^ ((h >> 1) & 3)) << 4);
        af[m] = *(const bf16x8*)((const char*)lds + ab);
      }
#pragma unroll
      for (int n = 0; n < 4; ++n)
        bfr[n] = *(const bf16x8*)((const char*)lds + slotR * 8192 + boffs[n]);
      int c02, tap2;
      if (tap <= 6) { c02 = c0; tap2 = tap + 2; }
      else { c02 = c0 + 1; tap2 = tap - 7; }
      if (c02 > 7) { c02 = 7; tap2 = 8; }  // tail dup, keeps vmcnt uniform
      stageB(c02, tap2, (c0 + tap + 2) & 3);
      __builtin_amdgcn_s_setprio(1);
#pragma unroll
      for (int m = 0; m < 8; ++m)
#pragma unroll
        for (int n = 0; n < 4; ++n)
          acc[m][n] = __builtin_amdgcn_mfma_f32_16x16x32_bf16(af[m], bfr[n],
                                                              acc[m][n], 0, 0, 0);
      __builtin_amdgcn_s_setprio(0);
    }
  }

  // epilogue: D row=(lane>>4)*4+reg is p, col=lane&15 is cout
#pragma unroll
  for (int m = 0; m < 8; ++m) {
    const int p = p0 + wm * 128 + (m >> 2) * 64 + (m & 3) * 16 + (lhi << 2);
#pragma unroll
    for (int n = 0; n < 4; ++n) {
      const int co = nh * 128 + wn * 64 + n * 16 + l15;
      float* dst = out + ((size_t)(b * 256 + co) << 12) + p;
      *reinterpret_cast<f32x4*>(dst) = acc[m][n];
    }
  }
}

extern "C" void kernel_launch(void* const* d_in, const int* in_sizes, int n_in,
                              void* d_out, int out_size, void* d_ws, size_t ws_size,
                              hipStream_t stream) {
  const float* x = (const float*)d_in[0];
  const float* w1 = (const float*)d_in[1];
  const float* bng = (const float*)d_in[2];
  const float* bnb = (const float*)d_in[3];
  const float* bnm = (const float*)d_in[4];
  const float* bnv = (const float*)d_in[5];
  const float* w2 = (const float*)d_in[6];
  const float* wgt = (const float*)d_in[7];
  float* out = (float*)d_out;

  char* ws = (char*)d_ws;
  const size_t xtp_bytes = (size_t)16 * 4356 * 256 * 2;    // 35,684,352
  const size_t agg_bytes = (size_t)16 * 9 * 256 * 256 * 2; // 18,874,368
  unsigned short* xTp = (unsigned short*)ws;
  unsigned short* agg = (unsigned short*)(ws + xtp_bytes);
  float* pooled = (float*)(ws + xtp_bytes + agg_bytes);
  float* att = (float*)(ws + xtp_bytes + agg_bytes + 16384);
  float* part = (float*)(ws + xtp_bytes + agg_bytes + 20480);

  transpose_kernel<<<1024, 256, 0, stream>>>(x, xTp, part);
  poolfin_kernel<<<16, 256, 0, stream>>>(part, pooled);
  attn_kernel<<<1, 256, 0, stream>>>(pooled, w1, bng, bnb, bnm, bnv, w2, att);
  agg_kernel<<<dim3(256, 2), 256, 0, stream>>>(att, wgt, agg);
  conv_kernel<<<512, 256, 0, stream>>>(xTp, agg, out);
}

// Round 13
// 108.054 us; speedup vs baseline: 1.3101x; 1.0246x over previous
//
#include <hip/hip_runtime.h>

typedef __attribute__((ext_vector_type(8))) short bf16x8;
typedef __attribute__((ext_vector_type(4))) float f32x4;

#define AS3 __attribute__((address_space(3)))
#define AS1 __attribute__((address_space(1)))

__device__ __forceinline__ unsigned short f2bf(float f) {
  unsigned u = __float_as_uint(f);
  u += 0x7fffu + ((u >> 16) & 1u);
  return (unsigned short)(u >> 16);
}
__device__ __forceinline__ float bf2f(unsigned short v) {
  return __uint_as_float((unsigned)v << 16);
}

// ---------------- kernel 1: transpose + pad + bf16 + border-zero + pool partials
__global__ void transpose_kernel(const float* __restrict__ x,
                                 unsigned short* __restrict__ xTp,
                                 float* __restrict__ part) {
  __shared__ unsigned short tb[64][258];
  __shared__ float redf[4][256];
  const int blk = blockIdx.x;
  const int b = blk >> 6, y = blk & 63;
  const int t = threadIdx.x;
  const int l = t & 63, w = t >> 6;
  const int coff = l >> 4;
  const int x4 = (l & 15) << 2;
  const float* src = x + (size_t)b * 256 * 4096 + (size_t)y * 64;
#pragma unroll 4
  for (int i = 0; i < 16; ++i) {
    const int c = w * 64 + i * 4 + coff;
    const float4 v = *reinterpret_cast<const float4*>(&src[(size_t)c * 4096 + x4]);
    tb[x4 + 0][c] = f2bf(v.x);
    tb[x4 + 1][c] = f2bf(v.y);
    tb[x4 + 2][c] = f2bf(v.z);
    tb[x4 + 3][c] = f2bf(v.w);
  }
  __syncthreads();
  unsigned short* dstb = xTp + (size_t)b * (4356 * 256);
  unsigned short* dst = dstb + ((size_t)(y + 1) * 66 + 1) * 256;
  float s0 = 0.f, s1 = 0.f, s2 = 0.f, s3 = 0.f;
#pragma unroll 4
  for (int i = 0; i < 16; ++i) {
    const int xx = w * 16 + i;
    ushort2 v0 = *(const ushort2*)&tb[xx][l * 4];
    ushort2 v1 = *(const ushort2*)&tb[xx][l * 4 + 2];
    s0 += bf2f(v0.x); s1 += bf2f(v0.y); s2 += bf2f(v1.x); s3 += bf2f(v1.y);
    ushort4 v = {v0.x, v0.y, v1.x, v1.y};
    *(ushort4*)&dst[(size_t)xx * 256 + l * 4] = v;
  }
  redf[w][l * 4 + 0] = s0;
  redf[w][l * 4 + 1] = s1;
  redf[w][l * 4 + 2] = s2;
  redf[w][l * 4 + 3] = s3;
  unsigned short* rowpad = dstb + ((size_t)(y + 1) * 66) * 256;
  rowpad[t] = 0;
  rowpad[65 * 256 + t] = 0;
  if (y == 0)
    for (int xx = 0; xx < 66; ++xx) dstb[(size_t)xx * 256 + t] = 0;
  if (y == 63)
    for (int xx = 0; xx < 66; ++xx) dstb[(size_t)(65 * 66 + xx) * 256 + t] = 0;
  __syncthreads();
  part[((size_t)(b * 64 + y)) * 256 + t] =
      redf[0][t] + redf[1][t] + redf[2][t] + redf[3][t];
}

// ---------------- kernel 1c: finish pool ----------
__global__ void poolfin_kernel(const float* __restrict__ part,
                               float* __restrict__ pooled) {
  const int b = blockIdx.x, c = threadIdx.x;
  float s = 0.f;
  for (int y = 0; y < 64; ++y) s += part[((size_t)(b * 64 + y)) * 256 + c];
  pooled[b * 256 + c] = s * (1.0f / 4096.0f);
}

// ---------------- kernel 2: attention MLP + softmax ----------------
__global__ void attn_kernel(const float* __restrict__ pooled,
                            const float* __restrict__ w1,
                            const float* __restrict__ bng,
                            const float* __restrict__ bnb,
                            const float* __restrict__ bnm,
                            const float* __restrict__ bnv,
                            const float* __restrict__ w2,
                            float* __restrict__ att) {
  __shared__ float hbuf[256];
  const int t = threadIdx.x;
  const int b = t >> 4, i = t & 15;
  float s = 0.f;
  for (int c = 0; c < 256; ++c) s += pooled[b * 256 + c] * w1[i * 256 + c];
  float h = (s - bnm[i]) * rsqrtf(bnv[i] + 1e-5f) * bng[i] + bnb[i];
  hbuf[t] = fmaxf(h, 0.f);
  __syncthreads();
  if (t < 64) {
    const int bb = t >> 2, k = t & 3;
    float l = 0.f;
    for (int j = 0; j < 16; ++j) l += hbuf[bb * 16 + j] * w2[k * 16 + j];
    float m = l;
    m = fmaxf(m, __shfl_xor(m, 1, 64));
    m = fmaxf(m, __shfl_xor(m, 2, 64));
    float e = expf(l - m);
    float sum = e;
    sum += __shfl_xor(sum, 1, 64);
    sum += __shfl_xor(sum, 2, 64);
    att[bb * 4 + k] = e / sum;
  }
}

// ---------------- kernel 3: aggregate per-sample kernels ----------------
__global__ void agg_kernel(const float* __restrict__ att,
                           const float* __restrict__ wgt,
                           unsigned short* __restrict__ agg) {
  const int o = blockIdx.x;
  const int bh = blockIdx.y;
  const int c = threadIdx.x;
  float w[4][9];
#pragma unroll
  for (int k = 0; k < 4; ++k) {
    const float* wp = wgt + ((size_t)((k << 8) + o) * 256 + c) * 9;
#pragma unroll
    for (int t = 0; t < 9; ++t) w[k][t] = wp[t];
  }
  __shared__ float attS[64];
  if (c < 64) attS[c] = att[c];
  __syncthreads();
#pragma unroll 1
  for (int b = bh * 8; b < bh * 8 + 8; ++b) {
    const float a0 = attS[b * 4 + 0], a1 = attS[b * 4 + 1];
    const float a2 = attS[b * 4 + 2], a3 = attS[b * 4 + 3];
#pragma unroll
    for (int t = 0; t < 9; ++t) {
      const float v = a0 * w[0][t] + a1 * w[1][t] + a2 * w[2][t] + a3 * w[3][t];
      agg[(((size_t)(b * 9 + t) * 256) + o) * 256 + c] = f2bf(v);
    }
  }
}

// ---------------- kernel 4: per-sample implicit-GEMM conv (bf16 MFMA) ----
// R6 skeleton (70us proven): tile 256x128, 4 waves (2Mx2N) of 128x64,
// A-halo staged per c0 (reused 9 taps), B ring-4 stage-ahead-2, 1 barrier/tap.
// CHANGE (single mechanism): frag ds_reads for tap t+1 are issued at the END
// of tap t (after the MFMA cluster), so the block-wide LDS read queue is
// serviced while the matrix pipe drains tap t across the barrier.
// Safety: top-of-tap gate tightened vmcnt(2)->vmcnt(0) (free: only B(t+1),
// staged a full tap earlier, is outstanding) => after the top barrier both
// B(t) and B(t+1) are globally visible, making end-of-tap reads race-free.
__global__ __launch_bounds__(256, 2) void conv_kernel(
    const unsigned short* __restrict__ xTp,
    const unsigned short* __restrict__ agg,
    float* __restrict__ out) {
  __shared__ unsigned short lds[448 * 32 + 4 * 128 * 32];  // 61440 B
  AS3 char* ldsA3 = (AS3 char*)lds;
  AS3 char* ldsB3 = ((AS3 char*)lds) + 28672;

  const int bid = blockIdx.x;
  const int b = bid & 15;   // XCD = b%8
  const int rest = bid >> 4;
  const int mt = rest >> 1;
  const int nh = rest & 1;
  const int p0 = mt << 8;
  const int rowA0 = mt * 264;

  const int tid = threadIdx.x;
  const int lane = tid & 63;
  const int wave = tid >> 6;
  const int wm = wave >> 1;
  const int wn = wave & 1;

  const int srow = tid >> 2;
  const int scol = ((tid & 3) ^ ((tid >> 3) & 3)) << 3;
  const int sdst = srow * 64 + (tid & 3) * 16;

  const unsigned short* xbs =
      xTp + (size_t)b * (4356 * 256) + (size_t)rowA0 * 256 + scol;
  const unsigned short* aggs =
      agg + ((size_t)(b * 9) * 256 + nh * 128 + srow) * 256 + scol;

  auto stageA = [&](int c0) {
#pragma unroll
    for (int i = 0; i < 7; ++i) {
      const int h = srow + (i << 6);
      const int hs = h > 395 ? 395 : h;
      __builtin_amdgcn_global_load_lds(
          (const AS1 void*)(xbs + (size_t)hs * 256 + c0 * 32),
          (AS3 void*)(ldsA3 + sdst + (i << 12)), 16, 0, 0);
    }
  };
  auto stageB = [&](int c02, int tap2, int slot) {
#pragma unroll
    for (int j = 0; j < 2; ++j) {
      __builtin_amdgcn_global_load_lds(
          (const AS1 void*)(aggs + tap2 * 65536 + (j << 14) + c02 * 32),
          (AS3 void*)(ldsB3 + slot * 8192 + sdst + (j << 12)), 16, 0, 0);
    }
  };

  const int l15 = lane & 15;
  const int lhi = lane >> 4;
  const int hb0 = wm * 132 + l15;
  const int rslotB = (lhi ^ ((l15 >> 1) & 3)) << 4;
  int boffs[4];
#pragma unroll
  for (int n = 0; n < 4; ++n)
    boffs[n] = 28672 + (wn * 64 + n * 16 + l15) * 64 + rslotB;

  f32x4 acc[8][4];
#pragma unroll
  for (int m = 0; m < 8; ++m)
#pragma unroll
    for (int n = 0; n < 4; ++n) acc[m][n] = (f32x4){0.f, 0.f, 0.f, 0.f};

#define LDFRAGS(tt)                                                        \
  {                                                                        \
    const int dy_ = (tt) / 3, dx_ = (tt) % 3;                              \
    const int slotR_ = (c0 + (tt)) & 3;                                    \
    _Pragma("unroll") for (int m = 0; m < 8; ++m) {                        \
      const int h_ = hb0 + ((m >> 2) + dy_) * 66 + (m & 3) * 16 + dx_;     \
      af[m] = *(const bf16x8*)((const char*)lds + h_ * 64 +                \
                               ((lhi ^ ((h_ >> 1) & 3)) << 4));            \
    }                                                                      \
    _Pragma("unroll") for (int n = 0; n < 4; ++n)                          \
      bfr[n] = *(const bf16x8*)((const char*)lds + slotR_ * 8192 + boffs[n]); \
  }

  stageB(0, 0, 0);
  stageB(0, 1, 1);

#pragma unroll 1
  for (int c0 = 0; c0 < 8; ++c0) {
    __builtin_amdgcn_s_barrier();  // all waves consumed A(c0-1)
    stageA(c0);
    asm volatile("s_waitcnt vmcnt(0)" ::: "memory");
    __builtin_amdgcn_s_barrier();
    __builtin_amdgcn_sched_barrier(0);
    bf16x8 af[8], bfr[4];
    LDFRAGS(0);  // preload tap0 frags (B slot c0&3 drained above)
#pragma unroll
    for (int tap = 0; tap < 9; ++tap) {
      if (tap != 0) {
        // gate: only B(tap+1) (staged last tap) outstanding -> free drain;
        // after barrier, B(tap) AND B(tap+1) globally visible.
        asm volatile("s_waitcnt vmcnt(0)" ::: "memory");
        __builtin_amdgcn_s_barrier();
        __builtin_amdgcn_sched_barrier(0);
      }
      {  // stage B(tap+2)
        int c02, tap2;
        if (tap <= 6) { c02 = c0; tap2 = tap + 2; }
        else { c02 = c0 + 1; tap2 = tap - 7; }
        if (c02 > 7) { c02 = 7; tap2 = 8; }  // tail dup, uniform counts
        stageB(c02, tap2, (c0 + tap + 2) & 3);
      }
      __builtin_amdgcn_s_setprio(1);
#pragma unroll
      for (int m = 0; m < 8; ++m)
#pragma unroll
        for (int n = 0; n < 4; ++n)
          acc[m][n] = __builtin_amdgcn_mfma_f32_16x16x32_bf16(af[m], bfr[n],
                                                              acc[m][n], 0, 0, 0);
      __builtin_amdgcn_s_setprio(0);
      // end-of-tap: issue NEXT tap's frag reads (overwrites af/bfr -> WAR
      // keeps them after the MFMAs); they land under the barrier crossing
      // and the matrix-pipe drain of this tap.
      if (tap < 8) LDFRAGS(tap + 1);
    }
  }

  // epilogue: D row=(lane>>4)*4+reg is p, col=lane&15 is cout
#pragma unroll
  for (int m = 0; m < 8; ++m) {
    const int p = p0 + wm * 128 + (m >> 2) * 64 + (m & 3) * 16 + (lhi << 2);
#pragma unroll
    for (int n = 0; n < 4; ++n) {
      const int co = nh * 128 + wn * 64 + n * 16 + l15;
      float* dst = out + ((size_t)(b * 256 + co) << 12) + p;
      *reinterpret_cast<f32x4*>(dst) = acc[m][n];
    }
  }
#undef LDFRAGS
}

extern "C" void kernel_launch(void* const* d_in, const int* in_sizes, int n_in,
                              void* d_out, int out_size, void* d_ws, size_t ws_size,
                              hipStream_t stream) {
  const float* x = (const float*)d_in[0];
  const float* w1 = (const float*)d_in[1];
  const float* bng = (const float*)d_in[2];
  const float* bnb = (const float*)d_in[3];
  const float* bnm = (const float*)d_in[4];
  const float* bnv = (const float*)d_in[5];
  const float* w2 = (const float*)d_in[6];
  const float* wgt = (const float*)d_in[7];
  float* out = (float*)d_out;

  char* ws = (char*)d_ws;
  const size_t xtp_bytes = (size_t)16 * 4356 * 256 * 2;    // 35,684,352
  const size_t agg_bytes = (size_t)16 * 9 * 256 * 256 * 2; // 18,874,368
  unsigned short* xTp = (unsigned short*)ws;
  unsigned short* agg = (unsigned short*)(ws + xtp_bytes);
  float* pooled = (float*)(ws + xtp_bytes + agg_bytes);
  float* att = (float*)(ws + xtp_bytes + agg_bytes + 16384);
  float* part = (float*)(ws + xtp_bytes + agg_bytes + 20480);

  transpose_kernel<<<1024, 256, 0, stream>>>(x, xTp, part);
  poolfin_kernel<<<16, 256, 0, stream>>>(part, pooled);
  attn_kernel<<<1, 256, 0, stream>>>(pooled, w1, bng, bnb, bnm, bnv, w2, att);
  agg_kernel<<<dim3(256, 2), 256, 0, stream>>>(att, wgt, agg);
  conv_kernel<<<512, 256, 0, stream>>>(xTp, agg, out);
}